// Round 1
// baseline (94.814 us; speedup 1.0000x reference)
//
#include <hip/hip_runtime.h>

// Problem: B=2, DEC=ENC=512, H=256.
// dec:(2,512,256) enc:(2,512,256) W:(256,512) b_mlp:(256) w_out:(1,256) b_out:(1)
// dec_proj[r][d] = sum_h dec[r][h]*W[d][256+h]
// enc_projb[r][d] = sum_h enc[r][h]*W[d][h] + b_mlp[d]
// attn[b,q,e] = sum_h relu(dp[bq][h]+epb[be][h]) * w[h] + b_out

// ---------------- Kernel 1: fused projections (A · W^T) ----------------
// C rows 0..1023 = dec rows (koff=256), rows 1024..2047 = enc rows (koff=0, +bias)
// Tile: TM=64 rows x TN=32 cols, TK=64. 128 threads, 4x4 per thread.
#define TK 64

__global__ __launch_bounds__(128) void proj_kernel(
    const float* __restrict__ dec, const float* __restrict__ enc,
    const float* __restrict__ W, const float* __restrict__ bmlp,
    float* __restrict__ dp, float* __restrict__ epb)
{
    __shared__ float As[64][TK + 4];  // stride 68 floats: 16B-aligned rows, conflict-free reads
    __shared__ float Ws[32][TK + 4];

    const int tid = threadIdx.x;       // 0..127
    const int tx = tid & 7;            // 0..7  (col groups)
    const int ty = tid >> 3;           // 0..15 (row groups)
    const int rowTile = blockIdx.y;    // 0..31 (rows rowTile*64)
    const int colTile = blockIdx.x;    // 0..7  (d = colTile*32)
    const bool isEnc = rowTile >= 16;
    const float* __restrict__ A = isEnc ? enc : dec;
    const int arow0 = (rowTile & 15) * 64;  // row within tensor
    const int koff  = isEnc ? 0 : 256;
    const int d0    = colTile * 32;

    float acc[4][4] = {};

    const int quad = tid & 15;   // staging: float4 index within 64-float k-chunk

    for (int kc = 0; kc < 256; kc += TK) {
        // stage A tile: 64 rows x 64 k
        {
            const int rbase = tid >> 4;  // 0..7
            #pragma unroll
            for (int p = 0; p < 8; ++p) {
                const int r = rbase + p * 8;
                const float4 v = *(const float4*)&A[(arow0 + r) * 256 + kc + quad * 4];
                *(float4*)&As[r][quad * 4] = v;
            }
            // stage W tile: 32 d-rows x 64 k
            const int c0 = tid >> 4;  // 0..7
            #pragma unroll
            for (int p = 0; p < 4; ++p) {
                const int c = c0 + p * 8;
                const float4 v = *(const float4*)&W[(d0 + c) * 512 + koff + kc + quad * 4];
                *(float4*)&Ws[c][quad * 4] = v;
            }
        }
        __syncthreads();

        #pragma unroll 4
        for (int kk = 0; kk < TK; kk += 4) {
            float4 a[4], w[4];
            #pragma unroll
            for (int i = 0; i < 4; ++i) a[i] = *(float4*)&As[ty + i * 16][kk];
            #pragma unroll
            for (int j = 0; j < 4; ++j) w[j] = *(float4*)&Ws[tx + j * 8][kk];
            #pragma unroll
            for (int i = 0; i < 4; ++i)
                #pragma unroll
                for (int j = 0; j < 4; ++j) {
                    acc[i][j] += a[i].x * w[j].x;
                    acc[i][j] += a[i].y * w[j].y;
                    acc[i][j] += a[i].z * w[j].z;
                    acc[i][j] += a[i].w * w[j].w;
                }
        }
        __syncthreads();
    }

    float* __restrict__ out = isEnc ? epb : dp;
    #pragma unroll
    for (int i = 0; i < 4; ++i) {
        const int r = arow0 + ty + i * 16;
        #pragma unroll
        for (int j = 0; j < 4; ++j) {
            const int d = d0 + tx + j * 8;
            float v = acc[i][j];
            if (isEnc) v += bmlp[d];
            out[r * 256 + d] = v;
        }
    }
}

// ---------------- Kernel 2: fused relu-MLP attention scores ----------------
// Block: 32 q-rows x 32 e-cols for one batch. Full H=256 staged in LDS.
// 256 threads, 2x2 outputs/thread (spread mapping: q=ty,ty+16; e=tx,tx+16).
__global__ __launch_bounds__(256) void attn_kernel(
    const float* __restrict__ dp, const float* __restrict__ epb,
    const float* __restrict__ wout, const float* __restrict__ bout,
    float* __restrict__ out)
{
    __shared__ float dS[32][260];   // stride 260: 16B-aligned, banks spread by 4/row
    __shared__ float eS[32][260];
    __shared__ float wS[256];

    const int tid = threadIdx.x;
    const int tx = tid & 15;        // e group
    const int ty = tid >> 4;        // q group
    const int et = blockIdx.x;      // 0..15
    const int qt = blockIdx.y;      // 0..15
    const int b  = blockIdx.z;      // 0..1
    const int q0g = b * 512 + qt * 32;
    const int e0g = b * 512 + et * 32;

    // stage dp/ep tiles: 32 rows x 256 floats each; per wave: row-constant, lane=float4 idx
    {
        const int fq = tid & 63;
        const int r0 = tid >> 6;    // 0..3
        #pragma unroll
        for (int p = 0; p < 8; ++p) {
            const int r = r0 + p * 4;
            *(float4*)&dS[r][fq * 4] = *(const float4*)&dp[(q0g + r) * 256 + fq * 4];
            *(float4*)&eS[r][fq * 4] = *(const float4*)&epb[(e0g + r) * 256 + fq * 4];
        }
        if (tid < 64) *(float4*)&wS[tid * 4] = *(const float4*)&wout[tid * 4];
    }
    __syncthreads();

    const float bo = bout[0];
    float acc00 = 0.f, acc01 = 0.f, acc10 = 0.f, acc11 = 0.f;

    #pragma unroll 8
    for (int hq = 0; hq < 64; ++hq) {
        const float4 a0 = *(float4*)&dS[ty][hq * 4];
        const float4 a1 = *(float4*)&dS[ty + 16][hq * 4];
        const float4 b0 = *(float4*)&eS[tx][hq * 4];
        const float4 b1 = *(float4*)&eS[tx + 16][hq * 4];
        const float4 w  = *(float4*)&wS[hq * 4];

        #define MLP_STEP(c)                                     \
            acc00 += fmaxf(a0.c + b0.c, 0.f) * w.c;             \
            acc01 += fmaxf(a0.c + b1.c, 0.f) * w.c;             \
            acc10 += fmaxf(a1.c + b0.c, 0.f) * w.c;             \
            acc11 += fmaxf(a1.c + b1.c, 0.f) * w.c;
        MLP_STEP(x) MLP_STEP(y) MLP_STEP(z) MLP_STEP(w)
        #undef MLP_STEP
    }

    const int qa = qt * 32 + ty;        // local q in batch
    const int ea = et * 32 + tx;
    float* __restrict__ orow0 = out + (size_t)(b * 512 + qa) * 512;
    float* __restrict__ orow1 = out + (size_t)(b * 512 + qa + 16) * 512;
    orow0[ea]      = acc00 + bo;
    orow0[ea + 16] = acc01 + bo;
    orow1[ea]      = acc10 + bo;
    orow1[ea + 16] = acc11 + bo;
}

extern "C" void kernel_launch(void* const* d_in, const int* in_sizes, int n_in,
                              void* d_out, int out_size, void* d_ws, size_t ws_size,
                              hipStream_t stream) {
    const float* dec  = (const float*)d_in[0];
    const float* enc  = (const float*)d_in[1];
    const float* W    = (const float*)d_in[2];
    const float* bmlp = (const float*)d_in[3];
    const float* wout = (const float*)d_in[4];
    const float* bout = (const float*)d_in[5];
    float* outp = (float*)d_out;

    float* dp  = (float*)d_ws;                 // 1024*256 f32 = 1 MB
    float* epb = dp + 1024 * 256;              // 1 MB

    proj_kernel<<<dim3(8, 32), 128, 0, stream>>>(dec, enc, W, bmlp, dp, epb);
    attn_kernel<<<dim3(16, 16, 2), 256, 0, stream>>>(dp, epb, wout, bout, outp);
}